// Round 6
// baseline (842.804 us; speedup 1.0000x reference)
//
#include <hip/hip_runtime.h>

// GRU_43387759624777 — Round 6: R5 step structure, 2 waves/SIMD via 512 blocks.
//
// R5 post-mortem: 1554 cyc/step at 1 wave/SIMD; ~810 VALU-pipe + ~310 MFMA +
// ~400 exposed stall. R4's 2-block attempt kept 1 wave/SIMD (2x2 waves); the
// correct split is 512 blocks x 4 WAVES x 8 rows -> 8 waves/CU, 2 waves/SIMD:
// block B issues while block A stalls. Per-wave work unchanged (3 tiles, 18
// MFMA; A-tile rows 8..15 zero; gate math masked to lanes l<32).
// Also: trunc-based hi/lo split (and+sub+perm, ~3 instr/value vs ~11 RNE);
// combined error 2^-16 — fine vs 1.67e-3 threshold.
//
// Verified invariants (R3/R5, absmax~0): A/B-frag [dim0=lane&15][k=(lane>>4)*8+j];
// C/D col=lane&15, row=(lane>>4)*4+reg; terms Whi*hhi + Whi*hlo + Wlo*hhi;
// hfrag word = hi | (lo<<16), row stride 12 words.

#define HID 64
#define SEQ 1024
#define BATCH 4096
#define ROWS 8
#define THREADS 256

typedef __attribute__((ext_vector_type(8))) short short8;
typedef __attribute__((ext_vector_type(4))) float f32x4;
typedef __attribute__((ext_vector_type(4))) unsigned uint4v;

#define SEL_HI 0x05040100u  // word = lo16(w1w0 bytes): hi plane (low halves)
#define SEL_LO 0x07060302u  // lo plane (high halves)
#define SEL_PACK 0x07060302u // pack: resid[31:16]<<16 | h[31:16]

union FragU { uint4v u; short8 s; };

__device__ __forceinline__ short f2bf(float f) {   // RNE (weights only, once)
  unsigned u = __float_as_uint(f);
  u += 0x7fffu + ((u >> 16) & 1u);
  return (short)(u >> 16);
}
__device__ __forceinline__ float bf2f(short s) {
  return __uint_as_float(((unsigned)(unsigned short)s) << 16);
}
__device__ __forceinline__ float rcp_fast(float x) { return __builtin_amdgcn_rcpf(x); }

__global__ __launch_bounds__(THREADS, 2) void gru_mfma(
    const float* __restrict__ x,     // [B, T]
    const float* __restrict__ w_ih,  // [192, 1]
    const float* __restrict__ w_hh,  // [192, 64]
    const float* __restrict__ b_ih,  // [192]
    const float* __restrict__ b_hh,  // [192]
    const float* __restrict__ w1,    // [32, 64]
    const float* __restrict__ b1,    // [32]
    const float* __restrict__ w2,    // [16, 32]
    const float* __restrict__ b2,    // [16]
    const float* __restrict__ w3,    // [1, 16]
    const float* __restrict__ b3,    // [1]
    float* __restrict__ out)         // [B, 1]
{
  const int L  = threadIdx.x;        // 0..255
  const int l  = L & 63;             // lane in wave
  const int wv = L >> 6;             // wave 0..3
  const int r0 = blockIdx.x * ROWS;  // first batch row

  // ---------------- LDS (~15 KB -> 2 blocks/CU) ----------------
  __shared__ __align__(16) unsigned hfrag[2][2][64][12]; // 12 KB, dbuf A-frags
  __shared__ float xbuf[ROWS][68];
  __shared__ float ybuf1[ROWS][36];
  __shared__ float ybuf2[ROWS][20];

  // ---------------- W fragments (registers, once) ----------------
  // Wave wv owns tiles ntg = gate*4 + wv: columns u = 16wv..16wv+15, all gates.
  short8 bhi[3][2], blo[3][2];
  {
    const int n0 = l & 15, q = l >> 4;
    #pragma unroll
    for (int gate = 0; gate < 3; ++gate) {
      const int c = (gate * 4 + wv) * 16 + n0;
      #pragma unroll
      for (int kt = 0; kt < 2; ++kt) {
        const float* p = w_hh + c * HID + kt * 32 + q * 8;
        f32x4 p0 = *(const f32x4*)p;
        f32x4 p1 = *(const f32x4*)(p + 4);
        float vals[8] = {p0[0], p0[1], p0[2], p0[3], p1[0], p1[1], p1[2], p1[3]};
        short8 hi8, lo8;
        #pragma unroll
        for (int j = 0; j < 8; ++j) {
          short h8 = f2bf(vals[j]);
          hi8[j] = h8;
          lo8[j] = f2bf(vals[j] - bf2f(h8));
        }
        bhi[gate][kt] = hi8;
        blo[gate][kt] = lo8;
      }
    }
  }

  // ---------------- per-lane elementwise constants ----------------
  // Lane owns unit u = 16wv + (l&15), rows 4qq..4qq+3 — valid only qq<2 (8 rows).
  const int u  = 16 * wv + (l & 15);
  const int qq = l >> 4;
  const float wir = w_ih[u], wiz = w_ih[64 + u], win = w_ih[128 + u];
  const float br  = b_ih[u] + b_hh[u];
  const float bz  = b_ih[64 + u] + b_hh[64 + u];
  const float bni = b_ih[128 + u];
  const float bnh = b_hh[128 + u];
  float h[4] = {0.f, 0.f, 0.f, 0.f};

  const int wkt = u >> 5;
  const int wQ  = (u >> 3) & 3;
  const int wj  = u & 7;

  // zero hfrag (h0 = 0; also keeps A-tile rows 8..15 zero forever)
  for (int i = L; i < 2 * 2 * 64 * 12; i += THREADS) ((unsigned*)hfrag)[i] = 0u;

  const float* xblk = x + (size_t)r0 * SEQ;

  // ---------------- scan ----------------
  for (int tb = 0; tb < SEQ / 64; ++tb) {
    __syncthreads();  // prior xbuf reads complete
    if (L < 16 * ROWS) {
      const int row = L >> 4, tq = L & 15;   // 8 rows x 16 quads = 128 threads
      f32x4 v = *(const f32x4*)(xblk + (size_t)row * SEQ + tb * 64 + tq * 4);
      *(f32x4*)&xbuf[row][tq * 4] = v;
    }
    #pragma unroll 2
    for (int s = 0; s < 64; ++s) {
      const int cur = s & 1, nxt = cur ^ 1;
      __syncthreads();  // prev step's hfrag writes + xbuf staging visible

      // ---- A-fragments: packed words -> hi/lo planes via v_perm ----
      uint4v k0a = *(const uint4v*)&hfrag[cur][0][l][0];
      uint4v k0b = *(const uint4v*)&hfrag[cur][0][l][4];
      uint4v k1a = *(const uint4v*)&hfrag[cur][1][l][0];
      uint4v k1b = *(const uint4v*)&hfrag[cur][1][l][4];
      FragU ahi0, alo0, ahi1, alo1;
      #pragma unroll
      for (int p = 0; p < 2; ++p) {
        ahi0.u[p]     = __builtin_amdgcn_perm(k0a[2*p+1], k0a[2*p], SEL_HI);
        alo0.u[p]     = __builtin_amdgcn_perm(k0a[2*p+1], k0a[2*p], SEL_LO);
        ahi0.u[p + 2] = __builtin_amdgcn_perm(k0b[2*p+1], k0b[2*p], SEL_HI);
        alo0.u[p + 2] = __builtin_amdgcn_perm(k0b[2*p+1], k0b[2*p], SEL_LO);
        ahi1.u[p]     = __builtin_amdgcn_perm(k1a[2*p+1], k1a[2*p], SEL_HI);
        alo1.u[p]     = __builtin_amdgcn_perm(k1a[2*p+1], k1a[2*p], SEL_LO);
        ahi1.u[p + 2] = __builtin_amdgcn_perm(k1b[2*p+1], k1b[2*p], SEL_HI);
        alo1.u[p + 2] = __builtin_amdgcn_perm(k1b[2*p+1], k1b[2*p], SEL_LO);
      }

      // ---- MFMA: 3 gates x (Whi*hhi + Whi*hlo + Wlo*hhi), K=64 ----
      f32x4 acc[3];
      #pragma unroll
      for (int gate = 0; gate < 3; ++gate) {
        f32x4 a = {0.f, 0.f, 0.f, 0.f};
        a = __builtin_amdgcn_mfma_f32_16x16x32_bf16(ahi0.s, bhi[gate][0], a, 0, 0, 0);
        a = __builtin_amdgcn_mfma_f32_16x16x32_bf16(ahi1.s, bhi[gate][1], a, 0, 0, 0);
        a = __builtin_amdgcn_mfma_f32_16x16x32_bf16(alo0.s, bhi[gate][0], a, 0, 0, 0);
        a = __builtin_amdgcn_mfma_f32_16x16x32_bf16(alo1.s, bhi[gate][1], a, 0, 0, 0);
        a = __builtin_amdgcn_mfma_f32_16x16x32_bf16(ahi0.s, blo[gate][0], a, 0, 0, 0);
        a = __builtin_amdgcn_mfma_f32_16x16x32_bf16(ahi1.s, blo[gate][1], a, 0, 0, 0);
        acc[gate] = a;
      }

      // ---- gates + h update on D layout (rows 4qq+r; valid rows < 8) ----
      if (qq < 2) {
        #pragma unroll
        for (int r = 0; r < 4; ++r) {
          const float xt = xbuf[4 * qq + r][s];
          float rpre = acc[0][r] + __fmaf_rn(xt, wir, br);
          float rr   = rcp_fast(1.0f + __expf(-rpre));
          float zpre = acc[1][r] + __fmaf_rn(xt, wiz, bz);
          float zz   = rcp_fast(1.0f + __expf(-zpre));
          float npre = __fmaf_rn(rr, acc[2][r] + bnh, __fmaf_rn(xt, win, bni));
          float nn   = 1.0f - 2.0f * rcp_fast(__expf(2.0f * npre) + 1.0f);
          h[r] = __fmaf_rn(zz, h[r] - nn, nn);
          // trunc split: hi = h[31:16], resid = h - hi (exact), lo = resid[31:16]
          float hif   = __uint_as_float(__float_as_uint(h[r]) & 0xFFFF0000u);
          float resid = h[r] - hif;
          unsigned word = __builtin_amdgcn_perm(__float_as_uint(resid),
                                                __float_as_uint(h[r]), SEL_PACK);
          hfrag[nxt][wkt][16 * wQ + 4 * qq + r][wj] = word;
        }
      }
    }
  }

  // ---------------- MLP head: 64 -> 32 -> 16 -> 1 ----------------
  __syncthreads();
  if (qq < 2) {
    #pragma unroll
    for (int r = 0; r < 4; ++r) xbuf[4 * qq + r][u] = h[r];
  }
  __syncthreads();

  {
    const int o = L & 31, row = L >> 5;          // 8 rows x 32 outs = 256 tasks
    float a = b1[o];
    #pragma unroll
    for (int j4 = 0; j4 < 16; ++j4) {
      f32x4 wv4 = *(const f32x4*)&w1[o * 64 + 4 * j4];
      f32x4 hv  = *(const f32x4*)&xbuf[row][4 * j4];
      a += wv4[0] * hv[0] + wv4[1] * hv[1] + wv4[2] * hv[2] + wv4[3] * hv[3];
    }
    ybuf1[row][o] = (a > 0.0f) ? a : 0.01f * a;
  }
  __syncthreads();

  if (L < 16 * ROWS) {
    const int o = L & 15, row = L >> 4;          // 8 rows x 16 outs = 128 tasks
    float a = b2[o];
    #pragma unroll
    for (int j4 = 0; j4 < 8; ++j4) {
      f32x4 wv4 = *(const f32x4*)&w2[o * 32 + 4 * j4];
      f32x4 yv  = *(const f32x4*)&ybuf1[row][4 * j4];
      a += wv4[0] * yv[0] + wv4[1] * yv[1] + wv4[2] * yv[2] + wv4[3] * yv[3];
    }
    ybuf2[row][o] = (a > 0.0f) ? a : 0.01f * a;
  }
  __syncthreads();

  if (L < ROWS) {
    float a = b3[0];
    #pragma unroll
    for (int j = 0; j < 16; ++j) a = __fmaf_rn(w3[j], ybuf2[L][j], a);
    out[r0 + L] = a;
  }
}

extern "C" void kernel_launch(void* const* d_in, const int* in_sizes, int n_in,
                              void* d_out, int out_size, void* d_ws, size_t ws_size,
                              hipStream_t stream) {
  const float* x    = (const float*)d_in[0];
  const float* w_ih = (const float*)d_in[1];
  const float* w_hh = (const float*)d_in[2];
  const float* b_ih = (const float*)d_in[3];
  const float* b_hh = (const float*)d_in[4];
  const float* w1   = (const float*)d_in[5];
  const float* b1   = (const float*)d_in[6];
  const float* w2   = (const float*)d_in[7];
  const float* b2   = (const float*)d_in[8];
  const float* w3   = (const float*)d_in[9];
  const float* b3   = (const float*)d_in[10];
  float* out = (float*)d_out;

  dim3 grid(BATCH / ROWS);  // 512 blocks x 4 waves -> 2 blocks/CU, 2 waves/SIMD
  dim3 block(THREADS);
  hipLaunchKernelGGL(gru_mfma, grid, block, 0, stream,
                     x, w_ih, w_hh, b_ih, b_hh, w1, b1, w2, b2, w3, b3, out);
}

// Round 7
// 638.011 us; speedup vs baseline: 1.3210x; 1.3210x over previous
//
#include <hip/hip_runtime.h>

// GRU_43387759624777 — Round 7: R5 structure + broken MFMA chains + x prefetch.
//
// R6 post-mortem: ROWS<16 duplicates per-wave overhead chip-wide (R4, R6 both
// regressed) — 256 blocks x 4 waves x 16 rows is the work-conserving layout.
// R5/R6 VALUBusy algebra: per-wave-step = ~508 overhead + ~308 gate math.
// Dominant overhead: each gate's 6 MFMAs formed ONE dependent chain (~17 cyc
// per link, serialized ~306 cyc at 1 wave/SIMD). Fixes:
//  1) two accumulators per gate (chain A = kt0 terms, chain B = kt1 terms,
//     3-deep each; merge with 4 v_adds) -> 6 independent chains, ~110 cyc.
//  2) xbuf double-buffered, staged one tb ahead (global-load latency spans 64
//     steps); next-step x prefetched to registers -> off the critical path.
//
// Verified invariants (R3/R5, absmax~0): A/B-frag [dim0=lane&15][k=(lane>>4)*8+j];
// C/D col=lane&15, row=(lane>>4)*4+reg; terms Whi*hhi + Whi*hlo + Wlo*hhi;
// hfrag word = hi | (lo<<16), row stride 12 words (2-way bank alias = free).

#define HID 64
#define SEQ 1024
#define BATCH 4096
#define ROWS 16
#define THREADS 256
#define NTB (SEQ / 64)   // 16 t-blocks

typedef __attribute__((ext_vector_type(8))) short short8;
typedef __attribute__((ext_vector_type(4))) float f32x4;
typedef __attribute__((ext_vector_type(4))) unsigned uint4v;

#define SEL_HI 0x05040100u   // hi plane (low halves of packed words)
#define SEL_LO 0x07060302u   // lo plane (high halves)
#define SEL_PACK 0x07060302u // resid[31:16]<<16 | h[31:16]

union FragU { uint4v u; short8 s; };

__device__ __forceinline__ short f2bf(float f) {   // RNE (weights only, once)
  unsigned u = __float_as_uint(f);
  u += 0x7fffu + ((u >> 16) & 1u);
  return (short)(u >> 16);
}
__device__ __forceinline__ float bf2f(short s) {
  return __uint_as_float(((unsigned)(unsigned short)s) << 16);
}
__device__ __forceinline__ float rcp_fast(float x) { return __builtin_amdgcn_rcpf(x); }

__global__ __launch_bounds__(THREADS, 1) void gru_mfma(
    const float* __restrict__ x,     // [B, T]
    const float* __restrict__ w_ih,  // [192, 1]
    const float* __restrict__ w_hh,  // [192, 64]
    const float* __restrict__ b_ih,  // [192]
    const float* __restrict__ b_hh,  // [192]
    const float* __restrict__ w1,    // [32, 64]
    const float* __restrict__ b1,    // [32]
    const float* __restrict__ w2,    // [16, 32]
    const float* __restrict__ b2,    // [16]
    const float* __restrict__ w3,    // [1, 16]
    const float* __restrict__ b3,    // [1]
    float* __restrict__ out)         // [B, 1]
{
  const int L  = threadIdx.x;        // 0..255
  const int l  = L & 63;             // lane in wave
  const int wv = L >> 6;             // wave 0..3
  const int r0 = blockIdx.x * ROWS;  // first batch row

  // ---------------- LDS (~24.5 KB -> 1 block/CU) ----------------
  __shared__ __align__(16) unsigned hfrag[2][2][64][12]; // 12 KB dbuf A-frags
  __shared__ float xbuf[2][ROWS][68];                    // dbuf x chunks
  __shared__ float ybuf1[ROWS][36];
  __shared__ float ybuf2[ROWS][20];

  // ---------------- W fragments (registers, once) ----------------
  // Wave wv owns tiles ntg = gate*4 + wv: all 3 gates of units 16wv..16wv+15.
  short8 bhi[3][2], blo[3][2];
  {
    const int n0 = l & 15, q = l >> 4;
    #pragma unroll
    for (int gate = 0; gate < 3; ++gate) {
      const int c = (gate * 4 + wv) * 16 + n0;
      #pragma unroll
      for (int kt = 0; kt < 2; ++kt) {
        const float* p = w_hh + c * HID + kt * 32 + q * 8;
        f32x4 p0 = *(const f32x4*)p;
        f32x4 p1 = *(const f32x4*)(p + 4);
        float vals[8] = {p0[0], p0[1], p0[2], p0[3], p1[0], p1[1], p1[2], p1[3]};
        short8 hi8, lo8;
        #pragma unroll
        for (int j = 0; j < 8; ++j) {
          short h8 = f2bf(vals[j]);
          hi8[j] = h8;
          lo8[j] = f2bf(vals[j] - bf2f(h8));
        }
        bhi[gate][kt] = hi8;
        blo[gate][kt] = lo8;
      }
    }
  }

  // ---------------- per-lane elementwise constants ----------------
  // Lane owns unit u = 16wv + (l&15), rows 4qq..4qq+3 (qq = l>>4, 0..3).
  const int u  = 16 * wv + (l & 15);
  const int qq = l >> 4;
  const float wir = w_ih[u], wiz = w_ih[64 + u], win = w_ih[128 + u];
  const float br  = b_ih[u] + b_hh[u];
  const float bz  = b_ih[64 + u] + b_hh[64 + u];
  const float bni = b_ih[128 + u];
  const float bnh = b_hh[128 + u];
  float h[4] = {0.f, 0.f, 0.f, 0.f};

  const int wkt = u >> 5;
  const int wQ  = (u >> 3) & 3;
  const int wj  = u & 7;

  // zero hfrag (h0 = 0)
  for (int i = L; i < 2 * 2 * 64 * 12; i += THREADS) ((unsigned*)hfrag)[i] = 0u;

  const float* xblk = x + (size_t)r0 * SEQ;
  const int srow = L >> 4, stq = L & 15;  // staging: 16 rows x 16 quads

  // stage tb=0 into xbuf[0] (visible after step-0 barrier)
  {
    f32x4 v = *(const f32x4*)(xblk + (size_t)srow * SEQ + stq * 4);
    *(f32x4*)&xbuf[0][srow][stq * 4] = v;
  }

  // ---------------- scan ----------------
  float xc0, xc1, xc2, xc3;   // current-step x for rows 4qq..4qq+3
  for (int tb = 0; tb < NTB; ++tb) {
    const int par = tb & 1;
    // issue next tb's global load now; ds_write happens after the s-loop
    // (64 steps of latency budget). Last tb re-loads tb=15 (unused, in-bounds).
    const int tbn = (tb < NTB - 1) ? tb + 1 : tb;
    f32x4 xg = *(const f32x4*)(xblk + (size_t)srow * SEQ + tbn * 64 + stq * 4);

    #pragma unroll 2
    for (int s = 0; s < 64; ++s) {
      const int cur = s & 1, nxt = cur ^ 1;
      __syncthreads();  // prev step's hfrag writes (and tb's xbuf) visible

      if (s == 0) {     // wave-uniform branch: load step-0 x (no prefetch yet)
        xc0 = xbuf[par][4 * qq + 0][0];
        xc1 = xbuf[par][4 * qq + 1][0];
        xc2 = xbuf[par][4 * qq + 2][0];
        xc3 = xbuf[par][4 * qq + 3][0];
      }
      // prefetch next step's x (s=63 reads pad col 64, discarded)
      float xn0 = xbuf[par][4 * qq + 0][s + 1];
      float xn1 = xbuf[par][4 * qq + 1][s + 1];
      float xn2 = xbuf[par][4 * qq + 2][s + 1];
      float xn3 = xbuf[par][4 * qq + 3][s + 1];

      // ---- A-fragments: packed words -> hi/lo planes via v_perm ----
      uint4v k0a = *(const uint4v*)&hfrag[cur][0][l][0];
      uint4v k0b = *(const uint4v*)&hfrag[cur][0][l][4];
      uint4v k1a = *(const uint4v*)&hfrag[cur][1][l][0];
      uint4v k1b = *(const uint4v*)&hfrag[cur][1][l][4];
      FragU ahi0, alo0, ahi1, alo1;
      #pragma unroll
      for (int p = 0; p < 2; ++p) {
        ahi0.u[p]     = __builtin_amdgcn_perm(k0a[2*p+1], k0a[2*p], SEL_HI);
        alo0.u[p]     = __builtin_amdgcn_perm(k0a[2*p+1], k0a[2*p], SEL_LO);
        ahi0.u[p + 2] = __builtin_amdgcn_perm(k0b[2*p+1], k0b[2*p], SEL_HI);
        alo0.u[p + 2] = __builtin_amdgcn_perm(k0b[2*p+1], k0b[2*p], SEL_LO);
        ahi1.u[p]     = __builtin_amdgcn_perm(k1a[2*p+1], k1a[2*p], SEL_HI);
        alo1.u[p]     = __builtin_amdgcn_perm(k1a[2*p+1], k1a[2*p], SEL_LO);
        ahi1.u[p + 2] = __builtin_amdgcn_perm(k1b[2*p+1], k1b[2*p], SEL_HI);
        alo1.u[p + 2] = __builtin_amdgcn_perm(k1b[2*p+1], k1b[2*p], SEL_LO);
      }

      // ---- MFMA: per gate TWO independent 3-chains (kt0 / kt1), then merge.
      // 6 independent chains total -> MFMA pipe pipelines instead of
      // serializing on one accumulator.
      f32x4 accA[3], accB[3];
      #pragma unroll
      for (int gate = 0; gate < 3; ++gate) {
        f32x4 a = {0.f, 0.f, 0.f, 0.f};
        f32x4 b = {0.f, 0.f, 0.f, 0.f};
        a = __builtin_amdgcn_mfma_f32_16x16x32_bf16(ahi0.s, bhi[gate][0], a, 0, 0, 0);
        b = __builtin_amdgcn_mfma_f32_16x16x32_bf16(ahi1.s, bhi[gate][1], b, 0, 0, 0);
        a = __builtin_amdgcn_mfma_f32_16x16x32_bf16(alo0.s, bhi[gate][0], a, 0, 0, 0);
        b = __builtin_amdgcn_mfma_f32_16x16x32_bf16(alo1.s, bhi[gate][1], b, 0, 0, 0);
        a = __builtin_amdgcn_mfma_f32_16x16x32_bf16(ahi0.s, blo[gate][0], a, 0, 0, 0);
        b = __builtin_amdgcn_mfma_f32_16x16x32_bf16(ahi1.s, blo[gate][1], b, 0, 0, 0);
        accA[gate] = a;
        accB[gate] = b;
      }

      // ---- gates + h update on D layout (row 4qq+r, unit u) ----
      const float xr[4] = {xc0, xc1, xc2, xc3};
      #pragma unroll
      for (int r = 0; r < 4; ++r) {
        const float xt = xr[r];
        float rpre = (accA[0][r] + accB[0][r]) + __fmaf_rn(xt, wir, br);
        float rr   = rcp_fast(1.0f + __expf(-rpre));
        float zpre = (accA[1][r] + accB[1][r]) + __fmaf_rn(xt, wiz, bz);
        float zz   = rcp_fast(1.0f + __expf(-zpre));
        float npre = __fmaf_rn(rr, (accA[2][r] + accB[2][r]) + bnh,
                               __fmaf_rn(xt, win, bni));
        float nn   = 1.0f - 2.0f * rcp_fast(__expf(2.0f * npre) + 1.0f);
        h[r] = __fmaf_rn(zz, h[r] - nn, nn);
        // trunc split: hi = h[31:16], resid = h - hi (exact), lo = resid[31:16]
        float hif   = __uint_as_float(__float_as_uint(h[r]) & 0xFFFF0000u);
        float resid = h[r] - hif;
        unsigned word = __builtin_amdgcn_perm(__float_as_uint(resid),
                                              __float_as_uint(h[r]), SEL_PACK);
        hfrag[nxt][wkt][16 * wQ + 4 * qq + r][wj] = word;
      }
      xc0 = xn0; xc1 = xn1; xc2 = xn2; xc3 = xn3;
    }

    // stage next tb's x (safe: readers of xbuf[par^1] finished 64 barriers ago;
    // consumers are >=1 barrier away)
    *(f32x4*)&xbuf[par ^ 1][srow][stq * 4] = xg;
  }

  // ---------------- MLP head: 64 -> 32 -> 16 -> 1 ----------------
  __syncthreads();
  #pragma unroll
  for (int r = 0; r < 4; ++r) xbuf[0][4 * qq + r][u] = h[r];  // h fp32 -> LDS
  __syncthreads();

  #pragma unroll
  for (int rep = 0; rep < 2; ++rep) {           // 16 rows x 32 outs = 512 tasks
    const int o = (L & 15) + 16 * rep;
    const int row = L >> 4;
    float a = b1[o];
    #pragma unroll
    for (int j4 = 0; j4 < 16; ++j4) {
      f32x4 wv4 = *(const f32x4*)&w1[o * 64 + 4 * j4];
      f32x4 hv  = *(const f32x4*)&xbuf[0][row][4 * j4];
      a += wv4[0] * hv[0] + wv4[1] * hv[1] + wv4[2] * hv[2] + wv4[3] * hv[3];
    }
    ybuf1[row][o] = (a > 0.0f) ? a : 0.01f * a;
  }
  __syncthreads();

  {
    const int o = L & 15;
    const int row = L >> 4;
    float a = b2[o];
    #pragma unroll
    for (int j4 = 0; j4 < 8; ++j4) {
      f32x4 wv4 = *(const f32x4*)&w2[o * 32 + 4 * j4];
      f32x4 yv  = *(const f32x4*)&ybuf1[row][4 * j4];
      a += wv4[0] * yv[0] + wv4[1] * yv[1] + wv4[2] * yv[2] + wv4[3] * yv[3];
    }
    ybuf2[row][o] = (a > 0.0f) ? a : 0.01f * a;
  }
  __syncthreads();

  if (L < ROWS) {
    float a = b3[0];
    #pragma unroll
    for (int j = 0; j < 16; ++j) a = __fmaf_rn(w3[j], ybuf2[L][j], a);
    out[r0 + L] = a;
  }
}

extern "C" void kernel_launch(void* const* d_in, const int* in_sizes, int n_in,
                              void* d_out, int out_size, void* d_ws, size_t ws_size,
                              hipStream_t stream) {
  const float* x    = (const float*)d_in[0];
  const float* w_ih = (const float*)d_in[1];
  const float* w_hh = (const float*)d_in[2];
  const float* b_ih = (const float*)d_in[3];
  const float* b_hh = (const float*)d_in[4];
  const float* w1   = (const float*)d_in[5];
  const float* b1   = (const float*)d_in[6];
  const float* w2   = (const float*)d_in[7];
  const float* b2   = (const float*)d_in[8];
  const float* w3   = (const float*)d_in[9];
  const float* b3   = (const float*)d_in[10];
  float* out = (float*)d_out;

  dim3 grid(BATCH / ROWS);  // 256 blocks x 4 waves x 16 rows — work-conserving
  dim3 block(THREADS);
  hipLaunchKernelGGL(gru_mfma, grid, block, 0, stream,
                     x, w_ih, w_hh, b_ih, b_hh, w1, b1, w2, b2, w3, b3, out);
}